// Round 4
// baseline (345.924 us; speedup 1.0000x reference)
//
#include <hip/hip_runtime.h>
#include <math.h>

#define GG 32
#define NV (GG * GG * GG)      // 32768 voxels
#define BB 4
#define DD 128

// Monotone order-preserving float->uint encoding.
__device__ __forceinline__ unsigned int enc_f(float f) {
    unsigned int u = __float_as_uint(f);
    return (u & 0x80000000u) ? ~u : (u | 0x80000000u);
}
__device__ __forceinline__ float dec_f(unsigned int u) {
    return __uint_as_float((u & 0x80000000u) ? (u ^ 0x80000000u) : ~u);
}
#define ENC_NEG_INF 0x007FFFFFu
#define ENC_POS_INF 0xFF800000u

// Tiny: one wave writes the 24 mm sentinel words.
__global__ void k_init_small(unsigned int* __restrict__ mm) {
    int i = threadIdx.x;
    if (i < BB * 6) mm[i] = ((i % 6) < 3) ? ENC_POS_INF : ENC_NEG_INF;
}

// grid (64, BB), block 256. Also zeroes cnt (BB*NV ints across 65536 threads;
// kernel boundary before k_idx orders the zeroing vs the atomicAdds).
__global__ void k_minmax(const float* __restrict__ xyz,
                         unsigned int* __restrict__ mm,
                         int* __restrict__ cnt, int N) {
    int b = blockIdx.y;
    int tid = threadIdx.x;
    int gid = blockIdx.x * blockDim.x + tid;
    int stride = gridDim.x * blockDim.x;

    int gtid = (blockIdx.y * gridDim.x + blockIdx.x) * blockDim.x + tid;
    int gtot = gridDim.x * gridDim.y * blockDim.x;   // 65536
    for (int j = gtid; j < BB * NV; j += gtot) cnt[j] = 0;

    float mn[3] = {INFINITY, INFINITY, INFINITY};
    float mx[3] = {-INFINITY, -INFINITY, -INFINITY};
    const float* base = xyz + (size_t)b * N * 3;
    for (int n = gid; n < N; n += stride) {
        const float* p = base + (size_t)n * 3;
        #pragma unroll
        for (int k = 0; k < 3; k++) {
            float v = p[k];
            mn[k] = fminf(mn[k], v);
            mx[k] = fmaxf(mx[k], v);
        }
    }
    for (int o = 32; o > 0; o >>= 1) {
        #pragma unroll
        for (int k = 0; k < 3; k++) {
            mn[k] = fminf(mn[k], __shfl_xor(mn[k], o));
            mx[k] = fmaxf(mx[k], __shfl_xor(mx[k], o));
        }
    }
    __shared__ float smn[4][3], smx[4][3];
    int w = tid >> 6;
    if ((tid & 63) == 0) {
        #pragma unroll
        for (int k = 0; k < 3; k++) { smn[w][k] = mn[k]; smx[w][k] = mx[k]; }
    }
    __syncthreads();
    if (tid == 0) {
        #pragma unroll
        for (int k = 0; k < 3; k++) {
            float a = fminf(fminf(smn[0][k], smn[1][k]), fminf(smn[2][k], smn[3][k]));
            float c = fmaxf(fmaxf(smx[0][k], smx[1][k]), fmaxf(smx[2][k], smx[3][k]));
            atomicMin(&mm[b * 6 + k], enc_f(a));
            atomicMax(&mm[b * 6 + 3 + k], enc_f(c));
        }
    }
}

__global__ void k_idx(const float* __restrict__ xyz,
                      const unsigned int* __restrict__ mm,
                      float* __restrict__ out_idx,
                      int* __restrict__ idx_i,
                      int* __restrict__ cnt, int N) {
    int n = blockIdx.x * blockDim.x + threadIdx.x;
    int b = blockIdx.y;
    if (n >= N) return;
    const float CLIP_HI = 1.0f - 1e-6f;
    const float* p = xyz + ((size_t)b * N + n) * 3;
    int vi[3];
    #pragma unroll
    for (int k = 0; k < 3; k++) {
        float mnv = dec_f(mm[b * 6 + k]);
        float mxv = dec_f(mm[b * 6 + 3 + k]);
        float rng = (mxv - mnv) + 1e-8f;
        float t = (p[k] - mnv) / rng;
        t = fminf(fmaxf(t, 0.0f), CLIP_HI);
        int q = (int)floorf(t * 32.0f);
        q = min(max(q, 0), GG - 1);
        vi[k] = q;
    }
    int idx = vi[0] * (GG * GG) + vi[1] * GG + vi[2];
    out_idx[(size_t)b * N + n] = (float)idx;
    if (idx_i) idx_i[(size_t)b * N + n] = idx;
    atomicAdd(&cnt[b * NV + idx], 1);
}

// Fused scatter-max: one block per (d, b); full voxel grid (128 KB) in LDS.
// 4x-unrolled point loop: 8 loads in flight before the 16 LDS atomics
// (memory-latency hiding at 4 waves/SIMD was the round-3 limiter).
__global__ __launch_bounds__(1024) void k_fuse(const float* __restrict__ feat,
                                               const int* __restrict__ idx_i,
                                               float* __restrict__ out, int N) {
    __shared__ unsigned int s[NV];
    int d = blockIdx.x;
    int b = blockIdx.y;
    int t = threadIdx.x;                       // 0..1023
    const int T = 1024;

    uint4* s4 = (uint4*)s;
    uint4 sent = make_uint4(ENC_NEG_INF, ENC_NEG_INF, ENC_NEG_INF, ENC_NEG_INF);
    #pragma unroll
    for (int v = 0; v < NV / 4 / T; v++) s4[v * T + t] = sent;
    __syncthreads();

    const float* fp = feat + ((size_t)b * DD + d) * N;
    const int*   ip = idx_i + (size_t)b * N;

    if ((N & 3) == 0) {
        const float4* f4 = (const float4*)fp;
        const int4*   i4 = (const int4*)ip;
        int n4 = N >> 2;
        int nfull = (n4 / (4 * T)) * (4 * T);
        int i = t;
        for (; i < nfull; i += 4 * T) {
            float4 f0 = f4[i];
            float4 f1 = f4[i + T];
            float4 f2 = f4[i + 2 * T];
            float4 f3 = f4[i + 3 * T];
            int4 x0 = i4[i];
            int4 x1 = i4[i + T];
            int4 x2 = i4[i + 2 * T];
            int4 x3 = i4[i + 3 * T];
            atomicMax(&s[x0.x], enc_f(f0.x));
            atomicMax(&s[x0.y], enc_f(f0.y));
            atomicMax(&s[x0.z], enc_f(f0.z));
            atomicMax(&s[x0.w], enc_f(f0.w));
            atomicMax(&s[x1.x], enc_f(f1.x));
            atomicMax(&s[x1.y], enc_f(f1.y));
            atomicMax(&s[x1.z], enc_f(f1.z));
            atomicMax(&s[x1.w], enc_f(f1.w));
            atomicMax(&s[x2.x], enc_f(f2.x));
            atomicMax(&s[x2.y], enc_f(f2.y));
            atomicMax(&s[x2.z], enc_f(f2.z));
            atomicMax(&s[x2.w], enc_f(f2.w));
            atomicMax(&s[x3.x], enc_f(f3.x));
            atomicMax(&s[x3.y], enc_f(f3.y));
            atomicMax(&s[x3.z], enc_f(f3.z));
            atomicMax(&s[x3.w], enc_f(f3.w));
        }
        for (; i < n4; i += T) {
            float4 f = f4[i];
            int4   x = i4[i];
            atomicMax(&s[x.x], enc_f(f.x));
            atomicMax(&s[x.y], enc_f(f.y));
            atomicMax(&s[x.z], enc_f(f.z));
            atomicMax(&s[x.w], enc_f(f.w));
        }
    } else {
        for (int i = t; i < N; i += T) atomicMax(&s[ip[i]], enc_f(fp[i]));
    }
    __syncthreads();

    float4* op = (float4*)(out + ((size_t)b * DD + d) * NV);
    #pragma unroll
    for (int r = 0; r < NV / 4 / T; r++) {
        int v = r * T + t;
        unsigned int u0 = s[4 * v + 0];
        unsigned int u1 = s[4 * v + 1];
        unsigned int u2 = s[4 * v + 2];
        unsigned int u3 = s[4 * v + 3];
        float4 o;
        o.x = (u0 == ENC_NEG_INF) ? 0.0f : dec_f(u0);
        o.y = (u1 == ENC_NEG_INF) ? 0.0f : dec_f(u1);
        o.z = (u2 == ENC_NEG_INF) ? 0.0f : dec_f(u2);
        o.w = (u3 == ENC_NEG_INF) ? 0.0f : dec_f(u3);
        op[v] = o;
    }
}

__global__ void k_fin_tail(float* __restrict__ out,
                           const unsigned int* __restrict__ mm,
                           long off_cnt, long off_mm) {
    int i = blockIdx.x * blockDim.x + threadIdx.x;
    if (i < BB * NV) {
        int c = ((const int*)out)[off_cnt + i];
        out[off_cnt + i] = (float)c;
    }
    if (i < BB * 3) {
        int b = i / 3, k = i % 3;
        out[off_mm + i]      = dec_f(mm[b * 6 + k]);
        out[off_mm + 12 + i] = dec_f(mm[b * 6 + 3 + k]);
    }
}

// ---- legacy fallback (tiny ws): atomics directly into out [B,D,V] ----

__global__ void k_init_legacy(unsigned int* __restrict__ out_u, long nvox,
                              unsigned int* __restrict__ mm,
                              unsigned int* __restrict__ cnt, long ncnt) {
    long i = blockIdx.x * (long)blockDim.x + threadIdx.x;
    long stride = gridDim.x * (long)blockDim.x;
    for (long j = i; j < nvox; j += stride) out_u[j] = ENC_NEG_INF;
    for (long j = i; j < ncnt; j += stride) cnt[j] = 0u;
    if (i < BB * 6) mm[i] = ((i % 6) < 3) ? ENC_POS_INF : ENC_NEG_INF;
}

__global__ void k_scatter_legacy(const float* __restrict__ feat,
                                 const float* __restrict__ out_idx,
                                 unsigned int* __restrict__ vox, int N) {
    int n = blockIdx.x * blockDim.x + threadIdx.x;
    int b = blockIdx.y;
    if (n >= N) return;
    int idx = (int)out_idx[(size_t)b * N + n];
    const float* fp = feat + (size_t)b * DD * N + n;
    unsigned int* vp = vox + (size_t)b * DD * NV + idx;
    #pragma unroll 4
    for (int d = 0; d < DD; d++) {
        atomicMax(vp + (size_t)d * NV, enc_f(fp[(size_t)d * N]));
    }
}

__global__ void k_fin_vox_legacy(unsigned int* __restrict__ out_u,
                                 const int* __restrict__ cnt) {
    size_t i = blockIdx.x * (size_t)blockDim.x + threadIdx.x;
    int b = (int)(i >> 22);
    int v = (int)(i & (NV - 1));
    unsigned int u = out_u[i];
    float f = (cnt[b * NV + v] == 0) ? 0.0f : dec_f(u);
    ((float*)out_u)[i] = f;
}

extern "C" void kernel_launch(void* const* d_in, const int* in_sizes, int n_in,
                              void* d_out, int out_size, void* d_ws, size_t ws_size,
                              hipStream_t stream) {
    const float* features = (const float*)d_in[0];   // [B, D, N]
    const float* xyz      = (const float*)d_in[1];   // [B, N, 3]
    int N = in_sizes[1] / (BB * 3);                  // 100000

    float* out = (float*)d_out;
    unsigned int* ws_u = (unsigned int*)d_ws;

    const long nvox    = (long)BB * DD * NV;
    const long off_idx = nvox;
    const long off_cnt = off_idx + (long)BB * N;
    const long ncnt    = (long)BB * NV;
    const long off_mm  = off_cnt + ncnt;

    float* out_idx = out + off_idx;
    int*   cnt     = (int*)(out + off_cnt);

    int nb = (N + 255) / 256;

    // fused path ws needs: idx_i [B*N] + mm [24]
    bool fused = ws_size >= (size_t)((long)BB * N + 24) * 4;

    if (fused) {
        int* idx_i = (int*)ws_u;
        unsigned int* mm = (unsigned int*)(idx_i + (long)BB * N);

        k_init_small<<<1, 64, 0, stream>>>(mm);
        k_minmax<<<dim3(64, BB), 256, 0, stream>>>(xyz, mm, cnt, N);
        k_idx<<<dim3(nb, BB), 256, 0, stream>>>(xyz, mm, out_idx, idx_i, cnt, N);
        k_fuse<<<dim3(DD, BB), 1024, 0, stream>>>(features, idx_i, out, N);
        k_fin_tail<<<(int)((ncnt + 255) / 256), 256, 0, stream>>>(out, mm, off_cnt, off_mm);
    } else {
        unsigned int* mm = ws_u;
        k_init_legacy<<<2048, 256, 0, stream>>>((unsigned int*)out, nvox, mm,
                                                (unsigned int*)cnt, ncnt);
        k_minmax<<<dim3(64, BB), 256, 0, stream>>>(xyz, mm, cnt, N);
        k_idx<<<dim3(nb, BB), 256, 0, stream>>>(xyz, mm, out_idx,
                                                (int*)NULL, cnt, N);
        k_scatter_legacy<<<dim3(nb, BB), 256, 0, stream>>>(features, out_idx,
                                                           (unsigned int*)out, N);
        k_fin_vox_legacy<<<(unsigned)(nvox / 256), 256, 0, stream>>>(
            (unsigned int*)out, cnt);
        k_fin_tail<<<(int)((ncnt + 255) / 256), 256, 0, stream>>>(out, mm, off_cnt, off_mm);
    }
}

// Round 5
// 342.878 us; speedup vs baseline: 1.0089x; 1.0089x over previous
//
#include <hip/hip_runtime.h>
#include <math.h>

#define GG 32
#define NV (GG * GG * GG)      // 32768 voxels
#define BB 4
#define DD 128

// Monotone order-preserving float->uint encoding.
__device__ __forceinline__ unsigned int enc_f(float f) {
    unsigned int u = __float_as_uint(f);
    return (u & 0x80000000u) ? ~u : (u | 0x80000000u);
}
__device__ __forceinline__ float dec_f(unsigned int u) {
    return __uint_as_float((u & 0x80000000u) ? (u ^ 0x80000000u) : ~u);
}
#define ENC_NEG_INF 0x007FFFFFu
#define ENC_POS_INF 0xFF800000u

// Tiny: one wave writes the 24 mm sentinel words.
__global__ void k_init_small(unsigned int* __restrict__ mm) {
    int i = threadIdx.x;
    if (i < BB * 6) mm[i] = ((i % 6) < 3) ? ENC_POS_INF : ENC_NEG_INF;
}

// grid (64, BB), block 256. Vectorized xyz (3x float4 = 4 points / iter).
// Also zeroes cnt (kernel boundary before k_idx orders zeroing vs atomics).
__global__ void k_minmax(const float* __restrict__ xyz,
                         unsigned int* __restrict__ mm,
                         int* __restrict__ cnt, int N) {
    int b = blockIdx.y;
    int tid = threadIdx.x;
    int gid = blockIdx.x * blockDim.x + tid;
    int stride = gridDim.x * blockDim.x;

    int gtid = (blockIdx.y * gridDim.x + blockIdx.x) * blockDim.x + tid;
    int gtot = gridDim.x * gridDim.y * blockDim.x;
    for (int j = gtid; j < BB * NV; j += gtot) cnt[j] = 0;

    float mn[3] = {INFINITY, INFINITY, INFINITY};
    float mx[3] = {-INFINITY, -INFINITY, -INFINITY};
    const float* base = xyz + (size_t)b * N * 3;
    const float4* p4 = (const float4*)base;
    int Ng = N >> 2;
    for (int g = gid; g < Ng; g += stride) {
        float4 a = p4[3 * g];
        float4 c = p4[3 * g + 1];
        float4 e = p4[3 * g + 2];
        // points: (a.x,a.y,a.z)(a.w,c.x,c.y)(c.z,c.w,e.x)(e.y,e.z,e.w)
        mn[0] = fminf(mn[0], fminf(fminf(a.x, a.w), fminf(c.z, e.y)));
        mx[0] = fmaxf(mx[0], fmaxf(fmaxf(a.x, a.w), fmaxf(c.z, e.y)));
        mn[1] = fminf(mn[1], fminf(fminf(a.y, c.x), fminf(c.w, e.z)));
        mx[1] = fmaxf(mx[1], fmaxf(fmaxf(a.y, c.x), fmaxf(c.w, e.z)));
        mn[2] = fminf(mn[2], fminf(fminf(a.z, c.y), fminf(e.x, e.w)));
        mx[2] = fmaxf(mx[2], fmaxf(fmaxf(a.z, c.y), fmaxf(e.x, e.w)));
    }
    for (int n = (Ng << 2) + gid; n < N; n += stride) {
        const float* p = base + (size_t)n * 3;
        #pragma unroll
        for (int k = 0; k < 3; k++) {
            float v = p[k];
            mn[k] = fminf(mn[k], v);
            mx[k] = fmaxf(mx[k], v);
        }
    }
    for (int o = 32; o > 0; o >>= 1) {
        #pragma unroll
        for (int k = 0; k < 3; k++) {
            mn[k] = fminf(mn[k], __shfl_xor(mn[k], o));
            mx[k] = fmaxf(mx[k], __shfl_xor(mx[k], o));
        }
    }
    __shared__ float smn[4][3], smx[4][3];
    int w = tid >> 6;
    if ((tid & 63) == 0) {
        #pragma unroll
        for (int k = 0; k < 3; k++) { smn[w][k] = mn[k]; smx[w][k] = mx[k]; }
    }
    __syncthreads();
    if (tid == 0) {
        #pragma unroll
        for (int k = 0; k < 3; k++) {
            float a = fminf(fminf(smn[0][k], smn[1][k]), fminf(smn[2][k], smn[3][k]));
            float c = fmaxf(fmaxf(smx[0][k], smx[1][k]), fmaxf(smx[2][k], smx[3][k]));
            atomicMin(&mm[b * 6 + k], enc_f(a));
            atomicMax(&mm[b * 6 + 3 + k], enc_f(c));
        }
    }
}

__device__ __forceinline__ int quant_idx(float x, float y, float z,
                                         const float* mnv, const float* mxv) {
    const float CLIP_HI = 1.0f - 1e-6f;
    float p[3] = {x, y, z};
    int vi[3];
    #pragma unroll
    for (int k = 0; k < 3; k++) {
        float rng = (mxv[k] - mnv[k]) + 1e-8f;
        float t = (p[k] - mnv[k]) / rng;      // keep ref op order bit-exact
        t = fminf(fmaxf(t, 0.0f), CLIP_HI);
        int q = (int)floorf(t * 32.0f);
        q = min(max(q, 0), GG - 1);
        vi[k] = q;
    }
    return vi[0] * (GG * GG) + vi[1] * GG + vi[2];
}

// 4 points per thread: 3x float4 in, float4 out_idx + int4 idx_i out.
__global__ void k_idx(const float* __restrict__ xyz,
                      const unsigned int* __restrict__ mm,
                      float* __restrict__ out_idx,
                      int* __restrict__ idx_i,
                      int* __restrict__ cnt, int N) {
    int g = blockIdx.x * blockDim.x + threadIdx.x;   // group of 4 points
    int b = blockIdx.y;
    float mnv[3], mxv[3];
    #pragma unroll
    for (int k = 0; k < 3; k++) {
        mnv[k] = dec_f(mm[b * 6 + k]);
        mxv[k] = dec_f(mm[b * 6 + 3 + k]);
    }
    int Ng = N >> 2;
    const float4* p4 = (const float4*)(xyz + (size_t)b * N * 3);
    if (g < Ng) {
        float4 a = p4[3 * g];
        float4 c = p4[3 * g + 1];
        float4 e = p4[3 * g + 2];
        int i0 = quant_idx(a.x, a.y, a.z, mnv, mxv);
        int i1 = quant_idx(a.w, c.x, c.y, mnv, mxv);
        int i2 = quant_idx(c.z, c.w, e.x, mnv, mxv);
        int i3 = quant_idx(e.y, e.z, e.w, mnv, mxv);
        size_t o = (size_t)b * N + 4 * (size_t)g;
        *(float4*)(out_idx + o) = make_float4((float)i0, (float)i1,
                                              (float)i2, (float)i3);
        if (idx_i) *(int4*)(idx_i + o) = make_int4(i0, i1, i2, i3);
        atomicAdd(&cnt[b * NV + i0], 1);
        atomicAdd(&cnt[b * NV + i1], 1);
        atomicAdd(&cnt[b * NV + i2], 1);
        atomicAdd(&cnt[b * NV + i3], 1);
    }
    if (g == 0) {   // serial tail (<=3 points)
        for (int n = Ng << 2; n < N; n++) {
            const float* p = xyz + ((size_t)b * N + n) * 3;
            int id = quant_idx(p[0], p[1], p[2], mnv, mxv);
            out_idx[(size_t)b * N + n] = (float)id;
            if (idx_i) idx_i[(size_t)b * N + n] = id;
            atomicAdd(&cnt[b * NV + id], 1);
        }
    }
}

// Fused scatter-max: one block per (d, b); full voxel grid (128 KB) in LDS.
// Extra blocks (d == DD) do the old k_fin_tail work (cnt->float, mm decode);
// safe because k_fuse launches after k_idx completes.
__global__ __launch_bounds__(1024) void k_fuse(const float* __restrict__ feat,
                                               const int* __restrict__ idx_i,
                                               float* __restrict__ out, int N,
                                               long off_cnt, long off_mm,
                                               const unsigned int* __restrict__ mm) {
    int d = blockIdx.x;
    int b = blockIdx.y;
    int t = threadIdx.x;                       // 0..1023
    const int T = 1024;

    if (d == DD) {
        int*   cp = (int*)out + off_cnt + (long)b * NV;
        float4* cf = (float4*)(out + off_cnt + (long)b * NV);
        const int4* ci = (const int4*)cp;
        #pragma unroll
        for (int r = 0; r < NV / 4 / T; r++) {
            int v = r * T + t;
            int4 x = ci[v];
            cf[v] = make_float4((float)x.x, (float)x.y, (float)x.z, (float)x.w);
        }
        if (t < 3) {
            out[off_mm + b * 3 + t]      = dec_f(mm[b * 6 + t]);
            out[off_mm + 12 + b * 3 + t] = dec_f(mm[b * 6 + 3 + t]);
        }
        return;
    }

    __shared__ unsigned int s[NV];
    uint4* s4 = (uint4*)s;
    uint4 sent = make_uint4(ENC_NEG_INF, ENC_NEG_INF, ENC_NEG_INF, ENC_NEG_INF);
    #pragma unroll
    for (int v = 0; v < NV / 4 / T; v++) s4[v * T + t] = sent;
    __syncthreads();

    const float* fp = feat + ((size_t)b * DD + d) * N;
    const int*   ip = idx_i + (size_t)b * N;

    if ((N & 3) == 0) {
        const float4* f4 = (const float4*)fp;
        const int4*   i4 = (const int4*)ip;
        int n4 = N >> 2;
        int nfull = (n4 / (4 * T)) * (4 * T);
        int i = t;
        for (; i < nfull; i += 4 * T) {
            float4 f0 = f4[i];
            float4 f1 = f4[i + T];
            float4 f2 = f4[i + 2 * T];
            float4 f3 = f4[i + 3 * T];
            int4 x0 = i4[i];
            int4 x1 = i4[i + T];
            int4 x2 = i4[i + 2 * T];
            int4 x3 = i4[i + 3 * T];
            atomicMax(&s[x0.x], enc_f(f0.x));
            atomicMax(&s[x0.y], enc_f(f0.y));
            atomicMax(&s[x0.z], enc_f(f0.z));
            atomicMax(&s[x0.w], enc_f(f0.w));
            atomicMax(&s[x1.x], enc_f(f1.x));
            atomicMax(&s[x1.y], enc_f(f1.y));
            atomicMax(&s[x1.z], enc_f(f1.z));
            atomicMax(&s[x1.w], enc_f(f1.w));
            atomicMax(&s[x2.x], enc_f(f2.x));
            atomicMax(&s[x2.y], enc_f(f2.y));
            atomicMax(&s[x2.z], enc_f(f2.z));
            atomicMax(&s[x2.w], enc_f(f2.w));
            atomicMax(&s[x3.x], enc_f(f3.x));
            atomicMax(&s[x3.y], enc_f(f3.y));
            atomicMax(&s[x3.z], enc_f(f3.z));
            atomicMax(&s[x3.w], enc_f(f3.w));
        }
        for (; i < n4; i += T) {
            float4 f = f4[i];
            int4   x = i4[i];
            atomicMax(&s[x.x], enc_f(f.x));
            atomicMax(&s[x.y], enc_f(f.y));
            atomicMax(&s[x.z], enc_f(f.z));
            atomicMax(&s[x.w], enc_f(f.w));
        }
    } else {
        for (int i = t; i < N; i += T) atomicMax(&s[ip[i]], enc_f(fp[i]));
    }
    __syncthreads();

    float4* op = (float4*)(out + ((size_t)b * DD + d) * NV);
    #pragma unroll
    for (int r = 0; r < NV / 4 / T; r++) {
        int v = r * T + t;
        unsigned int u0 = s[4 * v + 0];
        unsigned int u1 = s[4 * v + 1];
        unsigned int u2 = s[4 * v + 2];
        unsigned int u3 = s[4 * v + 3];
        float4 o;
        o.x = (u0 == ENC_NEG_INF) ? 0.0f : dec_f(u0);
        o.y = (u1 == ENC_NEG_INF) ? 0.0f : dec_f(u1);
        o.z = (u2 == ENC_NEG_INF) ? 0.0f : dec_f(u2);
        o.w = (u3 == ENC_NEG_INF) ? 0.0f : dec_f(u3);
        op[v] = o;
    }
}

__global__ void k_fin_tail(float* __restrict__ out,
                           const unsigned int* __restrict__ mm,
                           long off_cnt, long off_mm) {
    int i = blockIdx.x * blockDim.x + threadIdx.x;
    if (i < BB * NV) {
        int c = ((const int*)out)[off_cnt + i];
        out[off_cnt + i] = (float)c;
    }
    if (i < BB * 3) {
        int b = i / 3, k = i % 3;
        out[off_mm + i]      = dec_f(mm[b * 6 + k]);
        out[off_mm + 12 + i] = dec_f(mm[b * 6 + 3 + k]);
    }
}

// ---- legacy fallback (tiny ws): atomics directly into out [B,D,V] ----

__global__ void k_init_legacy(unsigned int* __restrict__ out_u, long nvox,
                              unsigned int* __restrict__ mm,
                              unsigned int* __restrict__ cnt, long ncnt) {
    long i = blockIdx.x * (long)blockDim.x + threadIdx.x;
    long stride = gridDim.x * (long)blockDim.x;
    for (long j = i; j < nvox; j += stride) out_u[j] = ENC_NEG_INF;
    for (long j = i; j < ncnt; j += stride) cnt[j] = 0u;
    if (i < BB * 6) mm[i] = ((i % 6) < 3) ? ENC_POS_INF : ENC_NEG_INF;
}

__global__ void k_scatter_legacy(const float* __restrict__ feat,
                                 const float* __restrict__ out_idx,
                                 unsigned int* __restrict__ vox, int N) {
    int n = blockIdx.x * blockDim.x + threadIdx.x;
    int b = blockIdx.y;
    if (n >= N) return;
    int idx = (int)out_idx[(size_t)b * N + n];
    const float* fp = feat + (size_t)b * DD * N + n;
    unsigned int* vp = vox + (size_t)b * DD * NV + idx;
    #pragma unroll 4
    for (int d = 0; d < DD; d++) {
        atomicMax(vp + (size_t)d * NV, enc_f(fp[(size_t)d * N]));
    }
}

__global__ void k_fin_vox_legacy(unsigned int* __restrict__ out_u,
                                 const int* __restrict__ cnt) {
    size_t i = blockIdx.x * (size_t)blockDim.x + threadIdx.x;
    int b = (int)(i >> 22);
    int v = (int)(i & (NV - 1));
    unsigned int u = out_u[i];
    float f = (cnt[b * NV + v] == 0) ? 0.0f : dec_f(u);
    ((float*)out_u)[i] = f;
}

extern "C" void kernel_launch(void* const* d_in, const int* in_sizes, int n_in,
                              void* d_out, int out_size, void* d_ws, size_t ws_size,
                              hipStream_t stream) {
    const float* features = (const float*)d_in[0];   // [B, D, N]
    const float* xyz      = (const float*)d_in[1];   // [B, N, 3]
    int N = in_sizes[1] / (BB * 3);                  // 100000

    float* out = (float*)d_out;
    unsigned int* ws_u = (unsigned int*)d_ws;

    const long nvox    = (long)BB * DD * NV;
    const long off_idx = nvox;
    const long off_cnt = off_idx + (long)BB * N;
    const long ncnt    = (long)BB * NV;
    const long off_mm  = off_cnt + ncnt;

    float* out_idx = out + off_idx;
    int*   cnt     = (int*)(out + off_cnt);

    int Ng = N >> 2;
    int nb4 = (Ng + 255) / 256; if (nb4 < 1) nb4 = 1;

    // fused path ws needs: idx_i [B*N] + mm [24]
    bool fused = ws_size >= (size_t)((long)BB * N + 24) * 4;

    if (fused) {
        int* idx_i = (int*)ws_u;
        unsigned int* mm = (unsigned int*)(idx_i + (long)BB * N);

        k_init_small<<<1, 64, 0, stream>>>(mm);
        k_minmax<<<dim3(64, BB), 256, 0, stream>>>(xyz, mm, cnt, N);
        k_idx<<<dim3(nb4, BB), 256, 0, stream>>>(xyz, mm, out_idx, idx_i, cnt, N);
        k_fuse<<<dim3(DD + 1, BB), 1024, 0, stream>>>(features, idx_i, out, N,
                                                      off_cnt, off_mm, mm);
    } else {
        unsigned int* mm = ws_u;
        k_init_legacy<<<2048, 256, 0, stream>>>((unsigned int*)out, nvox, mm,
                                                (unsigned int*)cnt, ncnt);
        k_minmax<<<dim3(64, BB), 256, 0, stream>>>(xyz, mm, cnt, N);
        k_idx<<<dim3(nb4, BB), 256, 0, stream>>>(xyz, mm, out_idx,
                                                 (int*)NULL, cnt, N);
        k_scatter_legacy<<<dim3((N + 255) / 256, BB), 256, 0, stream>>>(
            features, out_idx, (unsigned int*)out, N);
        k_fin_vox_legacy<<<(unsigned)(nvox / 256), 256, 0, stream>>>(
            (unsigned int*)out, cnt);
        k_fin_tail<<<(int)((ncnt + 255) / 256), 256, 0, stream>>>(out, mm, off_cnt, off_mm);
    }
}

// Round 6
// 320.598 us; speedup vs baseline: 1.0790x; 1.0695x over previous
//
#include <hip/hip_runtime.h>
#include <math.h>

#define GG 32
#define NV (GG * GG * GG)      // 32768 voxels
#define BB 4
#define DD 128

// Monotone order-preserving float->uint encoding.
__device__ __forceinline__ unsigned int enc_f(float f) {
    unsigned int u = __float_as_uint(f);
    return (u & 0x80000000u) ? ~u : (u | 0x80000000u);
}
__device__ __forceinline__ float dec_f(unsigned int u) {
    return __uint_as_float((u & 0x80000000u) ? (u ^ 0x80000000u) : ~u);
}
#define ENC_NEG_INF 0x007FFFFFu
#define ENC_POS_INF 0xFF800000u

// ---- non-temporal vector helpers (ext_vector types: clang-accepted) ----
typedef float        __attribute__((ext_vector_type(4))) f32x4;
typedef int          __attribute__((ext_vector_type(4))) i32x4;
typedef unsigned int __attribute__((ext_vector_type(4))) u32x4;

__device__ __forceinline__ float4 nt_loadf4(const float* p) {
    f32x4 v = __builtin_nontemporal_load((const f32x4*)p);
    return make_float4(v.x, v.y, v.z, v.w);
}
__device__ __forceinline__ void nt_storef4(float* p, float4 v) {
    f32x4 t = {v.x, v.y, v.z, v.w};
    __builtin_nontemporal_store(t, (f32x4*)p);
}

// Wave-0 reduction of the 64 per-block minmax partials for batch b.
// part layout: [(b*64 + blk)*6 + k], k<3 = mn, k>=3 = mx. Result -> sm[6].
__device__ __forceinline__ void reduce_partials(const float* __restrict__ part,
                                                int b, float* sm, int tid) {
    if (tid < 64) {
        float v[6];
        #pragma unroll
        for (int k = 0; k < 6; k++) v[k] = part[(b * 64 + tid) * 6 + k];
        for (int o = 32; o > 0; o >>= 1) {
            #pragma unroll
            for (int k = 0; k < 3; k++) {
                v[k]     = fminf(v[k],     __shfl_xor(v[k],     o));
                v[k + 3] = fmaxf(v[k + 3], __shfl_xor(v[k + 3], o));
            }
        }
        if (tid == 0) {
            #pragma unroll
            for (int k = 0; k < 6; k++) sm[k] = v[k];
        }
    }
    __syncthreads();
}

// grid (64, BB), block 256. Vectorized xyz (3x float4 = 4 points / iter).
// Writes per-block partials (no sentinel init, no atomics). Also zeroes cnt
// (kernel boundary before k_idx orders the zeroing vs the atomicAdds).
__global__ void k_minmax(const float* __restrict__ xyz,
                         float* __restrict__ part,
                         int* __restrict__ cnt, int N) {
    int b = blockIdx.y;
    int tid = threadIdx.x;
    int gid = blockIdx.x * blockDim.x + tid;
    int stride = gridDim.x * blockDim.x;

    int gtid = (blockIdx.y * gridDim.x + blockIdx.x) * blockDim.x + tid;
    int gtot = gridDim.x * gridDim.y * blockDim.x;
    for (int j = gtid; j < BB * NV; j += gtot) cnt[j] = 0;

    float mn[3] = {INFINITY, INFINITY, INFINITY};
    float mx[3] = {-INFINITY, -INFINITY, -INFINITY};
    const float* base = xyz + (size_t)b * N * 3;
    const float4* p4 = (const float4*)base;
    int Ng = N >> 2;
    for (int g = gid; g < Ng; g += stride) {
        float4 a = p4[3 * g];
        float4 c = p4[3 * g + 1];
        float4 e = p4[3 * g + 2];
        // points: (a.x,a.y,a.z)(a.w,c.x,c.y)(c.z,c.w,e.x)(e.y,e.z,e.w)
        mn[0] = fminf(mn[0], fminf(fminf(a.x, a.w), fminf(c.z, e.y)));
        mx[0] = fmaxf(mx[0], fmaxf(fmaxf(a.x, a.w), fmaxf(c.z, e.y)));
        mn[1] = fminf(mn[1], fminf(fminf(a.y, c.x), fminf(c.w, e.z)));
        mx[1] = fmaxf(mx[1], fmaxf(fmaxf(a.y, c.x), fmaxf(c.w, e.z)));
        mn[2] = fminf(mn[2], fminf(fminf(a.z, c.y), fminf(e.x, e.w)));
        mx[2] = fmaxf(mx[2], fmaxf(fmaxf(a.z, c.y), fmaxf(e.x, e.w)));
    }
    for (int n = (Ng << 2) + gid; n < N; n += stride) {
        const float* p = base + (size_t)n * 3;
        #pragma unroll
        for (int k = 0; k < 3; k++) {
            float v = p[k];
            mn[k] = fminf(mn[k], v);
            mx[k] = fmaxf(mx[k], v);
        }
    }
    for (int o = 32; o > 0; o >>= 1) {
        #pragma unroll
        for (int k = 0; k < 3; k++) {
            mn[k] = fminf(mn[k], __shfl_xor(mn[k], o));
            mx[k] = fmaxf(mx[k], __shfl_xor(mx[k], o));
        }
    }
    __shared__ float smn[4][3], smx[4][3];
    int w = tid >> 6;
    if ((tid & 63) == 0) {
        #pragma unroll
        for (int k = 0; k < 3; k++) { smn[w][k] = mn[k]; smx[w][k] = mx[k]; }
    }
    __syncthreads();
    if (tid == 0) {
        float* pb = part + ((size_t)b * 64 + blockIdx.x) * 6;
        #pragma unroll
        for (int k = 0; k < 3; k++) {
            pb[k]     = fminf(fminf(smn[0][k], smn[1][k]), fminf(smn[2][k], smn[3][k]));
            pb[3 + k] = fmaxf(fmaxf(smx[0][k], smx[1][k]), fmaxf(smx[2][k], smx[3][k]));
        }
    }
}

__device__ __forceinline__ int quant_idx(float x, float y, float z,
                                         const float* mnv, const float* mxv) {
    const float CLIP_HI = 1.0f - 1e-6f;
    float p[3] = {x, y, z};
    int vi[3];
    #pragma unroll
    for (int k = 0; k < 3; k++) {
        float rng = (mxv[k] - mnv[k]) + 1e-8f;
        float t = (p[k] - mnv[k]) / rng;      // keep ref op order bit-exact
        t = fminf(fmaxf(t, 0.0f), CLIP_HI);
        int q = (int)floorf(t * 32.0f);
        q = min(max(q, 0), GG - 1);
        vi[k] = q;
    }
    return vi[0] * (GG * GG) + vi[1] * GG + vi[2];
}

// 4 points per thread: 3x float4 in, float4 out_idx + int4 idx_i out.
// Reduces the 64 minmax partials in wave 0 (fmin/fmax are exact -> order-free).
__global__ void k_idx(const float* __restrict__ xyz,
                      const float* __restrict__ part,
                      float* __restrict__ out_idx,
                      int* __restrict__ idx_i,
                      int* __restrict__ cnt, int N) {
    int g = blockIdx.x * blockDim.x + threadIdx.x;   // group of 4 points
    int b = blockIdx.y;
    __shared__ float sm[6];
    reduce_partials(part, b, sm, threadIdx.x);
    float mnv[3] = {sm[0], sm[1], sm[2]};
    float mxv[3] = {sm[3], sm[4], sm[5]};

    int Ng = N >> 2;
    const float4* p4 = (const float4*)(xyz + (size_t)b * N * 3);
    if (g < Ng) {
        float4 a = p4[3 * g];
        float4 c = p4[3 * g + 1];
        float4 e = p4[3 * g + 2];
        int i0 = quant_idx(a.x, a.y, a.z, mnv, mxv);
        int i1 = quant_idx(a.w, c.x, c.y, mnv, mxv);
        int i2 = quant_idx(c.z, c.w, e.x, mnv, mxv);
        int i3 = quant_idx(e.y, e.z, e.w, mnv, mxv);
        size_t o = (size_t)b * N + 4 * (size_t)g;
        nt_storef4(out_idx + o, make_float4((float)i0, (float)i1,
                                            (float)i2, (float)i3));
        if (idx_i) *(int4*)(idx_i + o) = make_int4(i0, i1, i2, i3);
        atomicAdd(&cnt[b * NV + i0], 1);
        atomicAdd(&cnt[b * NV + i1], 1);
        atomicAdd(&cnt[b * NV + i2], 1);
        atomicAdd(&cnt[b * NV + i3], 1);
    }
    if (g == 0) {   // serial tail (<=3 points)
        for (int n = Ng << 2; n < N; n++) {
            const float* p = xyz + ((size_t)b * N + n) * 3;
            int id = quant_idx(p[0], p[1], p[2], mnv, mxv);
            out_idx[(size_t)b * N + n] = (float)id;
            if (idx_i) idx_i[(size_t)b * N + n] = id;
            atomicAdd(&cnt[b * NV + id], 1);
        }
    }
}

// Fused scatter-max: one block per (d, b); full voxel grid (128 KB) in LDS.
// blockIdx.x == 0 blocks (dispatched FIRST) do the tail work: cnt->float +
// minmax outputs. Main blocks: NT feat loads / NT out stores (touch-once,
// keeps idx_i L2-resident) + read-before-atomic (skips most LDS RMWs; benign
// race since the LDS value is monotone non-decreasing).
__global__ __launch_bounds__(1024) void k_fuse(const float* __restrict__ feat,
                                               const int* __restrict__ idx_i,
                                               float* __restrict__ out, int N,
                                               long off_cnt, long off_mm,
                                               const float* __restrict__ part) {
    int b = blockIdx.y;
    int t = threadIdx.x;                       // 0..1023
    const int T = 1024;
    __shared__ unsigned int s[NV];
    __shared__ float sm[6];

    if (blockIdx.x == 0) {
        int*    cp = (int*)out + off_cnt + (long)b * NV;
        float4* cf = (float4*)(out + off_cnt + (long)b * NV);
        const int4* ci = (const int4*)cp;
        #pragma unroll
        for (int r = 0; r < NV / 4 / T; r++) {
            int v = r * T + t;
            int4 x = ci[v];
            cf[v] = make_float4((float)x.x, (float)x.y, (float)x.z, (float)x.w);
        }
        reduce_partials(part, b, sm, t);
        if (t < 3) {
            out[off_mm + b * 3 + t]      = sm[t];
            out[off_mm + 12 + b * 3 + t] = sm[3 + t];
        }
        return;
    }
    int d = blockIdx.x - 1;

    uint4* s4 = (uint4*)s;
    uint4 sent = make_uint4(ENC_NEG_INF, ENC_NEG_INF, ENC_NEG_INF, ENC_NEG_INF);
    #pragma unroll
    for (int v = 0; v < NV / 4 / T; v++) s4[v * T + t] = sent;
    __syncthreads();

    const float* fp = feat + ((size_t)b * DD + d) * N;
    const int*   ip = idx_i + (size_t)b * N;

    if ((N & 3) == 0) {
        const int4* i4 = (const int4*)ip;
        int n4 = N >> 2;
        for (int i = t; i < n4; i += T) {
            float4 f = nt_loadf4(fp + 4 * (size_t)i);
            int4   x = i4[i];
            unsigned int e0 = enc_f(f.x);
            unsigned int e1 = enc_f(f.y);
            unsigned int e2 = enc_f(f.z);
            unsigned int e3 = enc_f(f.w);
            if (e0 > s[x.x]) atomicMax(&s[x.x], e0);
            if (e1 > s[x.y]) atomicMax(&s[x.y], e1);
            if (e2 > s[x.z]) atomicMax(&s[x.z], e2);
            if (e3 > s[x.w]) atomicMax(&s[x.w], e3);
        }
    } else {
        for (int i = t; i < N; i += T) {
            unsigned int e = enc_f(fp[i]);
            if (e > s[ip[i]]) atomicMax(&s[ip[i]], e);
        }
    }
    __syncthreads();

    float* op = out + ((size_t)b * DD + d) * NV;
    #pragma unroll
    for (int r = 0; r < NV / 4 / T; r++) {
        int v = r * T + t;
        unsigned int u0 = s[4 * v + 0];
        unsigned int u1 = s[4 * v + 1];
        unsigned int u2 = s[4 * v + 2];
        unsigned int u3 = s[4 * v + 3];
        float4 o;
        o.x = (u0 == ENC_NEG_INF) ? 0.0f : dec_f(u0);
        o.y = (u1 == ENC_NEG_INF) ? 0.0f : dec_f(u1);
        o.z = (u2 == ENC_NEG_INF) ? 0.0f : dec_f(u2);
        o.w = (u3 == ENC_NEG_INF) ? 0.0f : dec_f(u3);
        nt_storef4(op + 4 * (size_t)v, o);
    }
}

// ---- legacy fallback (tiny ws): atomics directly into out [B,D,V] ----

__global__ void k_minmax_legacy(const float* __restrict__ xyz,
                                unsigned int* __restrict__ mm,
                                int* __restrict__ cnt, int N) {
    int b = blockIdx.y;
    int tid = threadIdx.x;
    int gid = blockIdx.x * blockDim.x + tid;
    int stride = gridDim.x * blockDim.x;
    float mn[3] = {INFINITY, INFINITY, INFINITY};
    float mx[3] = {-INFINITY, -INFINITY, -INFINITY};
    const float* base = xyz + (size_t)b * N * 3;
    for (int n = gid; n < N; n += stride) {
        const float* p = base + (size_t)n * 3;
        #pragma unroll
        for (int k = 0; k < 3; k++) {
            float v = p[k];
            mn[k] = fminf(mn[k], v);
            mx[k] = fmaxf(mx[k], v);
        }
    }
    for (int o = 32; o > 0; o >>= 1) {
        #pragma unroll
        for (int k = 0; k < 3; k++) {
            mn[k] = fminf(mn[k], __shfl_xor(mn[k], o));
            mx[k] = fmaxf(mx[k], __shfl_xor(mx[k], o));
        }
    }
    __shared__ float smn[4][3], smx[4][3];
    int w = tid >> 6;
    if ((tid & 63) == 0) {
        #pragma unroll
        for (int k = 0; k < 3; k++) { smn[w][k] = mn[k]; smx[w][k] = mx[k]; }
    }
    __syncthreads();
    if (tid == 0) {
        #pragma unroll
        for (int k = 0; k < 3; k++) {
            float a = fminf(fminf(smn[0][k], smn[1][k]), fminf(smn[2][k], smn[3][k]));
            float c = fmaxf(fmaxf(smx[0][k], smx[1][k]), fmaxf(smx[2][k], smx[3][k]));
            atomicMin(&mm[b * 6 + k], enc_f(a));
            atomicMax(&mm[b * 6 + 3 + k], enc_f(c));
        }
    }
}

__global__ void k_idx_legacy(const float* __restrict__ xyz,
                             const unsigned int* __restrict__ mm,
                             float* __restrict__ out_idx,
                             int* __restrict__ cnt, int N) {
    int n = blockIdx.x * blockDim.x + threadIdx.x;
    int b = blockIdx.y;
    if (n >= N) return;
    float mnv[3], mxv[3];
    #pragma unroll
    for (int k = 0; k < 3; k++) {
        mnv[k] = dec_f(mm[b * 6 + k]);
        mxv[k] = dec_f(mm[b * 6 + 3 + k]);
    }
    const float* p = xyz + ((size_t)b * N + n) * 3;
    int idx = quant_idx(p[0], p[1], p[2], mnv, mxv);
    out_idx[(size_t)b * N + n] = (float)idx;
    atomicAdd(&cnt[b * NV + idx], 1);
}

__global__ void k_init_legacy(unsigned int* __restrict__ out_u, long nvox,
                              unsigned int* __restrict__ mm,
                              unsigned int* __restrict__ cnt, long ncnt) {
    long i = blockIdx.x * (long)blockDim.x + threadIdx.x;
    long stride = gridDim.x * (long)blockDim.x;
    for (long j = i; j < nvox; j += stride) out_u[j] = ENC_NEG_INF;
    for (long j = i; j < ncnt; j += stride) cnt[j] = 0u;
    if (i < BB * 6) mm[i] = ((i % 6) < 3) ? ENC_POS_INF : ENC_NEG_INF;
}

__global__ void k_scatter_legacy(const float* __restrict__ feat,
                                 const float* __restrict__ out_idx,
                                 unsigned int* __restrict__ vox, int N) {
    int n = blockIdx.x * blockDim.x + threadIdx.x;
    int b = blockIdx.y;
    if (n >= N) return;
    int idx = (int)out_idx[(size_t)b * N + n];
    const float* fp = feat + (size_t)b * DD * N + n;
    unsigned int* vp = vox + (size_t)b * DD * NV + idx;
    #pragma unroll 4
    for (int d = 0; d < DD; d++) {
        atomicMax(vp + (size_t)d * NV, enc_f(fp[(size_t)d * N]));
    }
}

__global__ void k_fin_vox_legacy(unsigned int* __restrict__ out_u,
                                 const int* __restrict__ cnt) {
    size_t i = blockIdx.x * (size_t)blockDim.x + threadIdx.x;
    int b = (int)(i >> 22);
    int v = (int)(i & (NV - 1));
    unsigned int u = out_u[i];
    float f = (cnt[b * NV + v] == 0) ? 0.0f : dec_f(u);
    ((float*)out_u)[i] = f;
}

__global__ void k_fin_tail_legacy(float* __restrict__ out,
                                  const unsigned int* __restrict__ mm,
                                  long off_cnt, long off_mm) {
    int i = blockIdx.x * blockDim.x + threadIdx.x;
    if (i < BB * NV) {
        int c = ((const int*)out)[off_cnt + i];
        out[off_cnt + i] = (float)c;
    }
    if (i < BB * 3) {
        int b = i / 3, k = i % 3;
        out[off_mm + i]      = dec_f(mm[b * 6 + k]);
        out[off_mm + 12 + i] = dec_f(mm[b * 6 + 3 + k]);
    }
}

extern "C" void kernel_launch(void* const* d_in, const int* in_sizes, int n_in,
                              void* d_out, int out_size, void* d_ws, size_t ws_size,
                              hipStream_t stream) {
    const float* features = (const float*)d_in[0];   // [B, D, N]
    const float* xyz      = (const float*)d_in[1];   // [B, N, 3]
    int N = in_sizes[1] / (BB * 3);                  // 100000

    float* out = (float*)d_out;
    unsigned int* ws_u = (unsigned int*)d_ws;

    const long nvox    = (long)BB * DD * NV;
    const long off_idx = nvox;
    const long off_cnt = off_idx + (long)BB * N;
    const long ncnt    = (long)BB * NV;
    const long off_mm  = off_cnt + ncnt;

    float* out_idx = out + off_idx;
    int*   cnt     = (int*)(out + off_cnt);

    int Ng = N >> 2;
    int nb4 = (Ng + 255) / 256; if (nb4 < 1) nb4 = 1;

    // fused path ws needs: idx_i [B*N] ints + part [B*64*6] floats
    bool fused = ws_size >= (size_t)((long)BB * N + (long)BB * 64 * 6) * 4;

    if (fused) {
        int*   idx_i = (int*)ws_u;
        float* part  = (float*)(idx_i + (long)BB * N);

        k_minmax<<<dim3(64, BB), 256, 0, stream>>>(xyz, part, cnt, N);
        k_idx<<<dim3(nb4, BB), 256, 0, stream>>>(xyz, part, out_idx, idx_i, cnt, N);
        k_fuse<<<dim3(DD + 1, BB), 1024, 0, stream>>>(features, idx_i, out, N,
                                                      off_cnt, off_mm, part);
    } else {
        unsigned int* mm = ws_u;
        k_init_legacy<<<2048, 256, 0, stream>>>((unsigned int*)out, nvox, mm,
                                                (unsigned int*)cnt, ncnt);
        k_minmax_legacy<<<dim3(64, BB), 256, 0, stream>>>(xyz, mm, cnt, N);
        k_idx_legacy<<<dim3((N + 255) / 256, BB), 256, 0, stream>>>(
            xyz, mm, out_idx, cnt, N);
        k_scatter_legacy<<<dim3((N + 255) / 256, BB), 256, 0, stream>>>(
            features, out_idx, (unsigned int*)out, N);
        k_fin_vox_legacy<<<(unsigned)(nvox / 256), 256, 0, stream>>>(
            (unsigned int*)out, cnt);
        k_fin_tail_legacy<<<(int)((ncnt + 255) / 256), 256, 0, stream>>>(
            out, mm, off_cnt, off_mm);
    }
}

// Round 7
// 310.236 us; speedup vs baseline: 1.1150x; 1.0334x over previous
//
#include <hip/hip_runtime.h>
#include <math.h>

#define GG 32
#define NV (GG * GG * GG)      // 32768 voxels
#define BB 4
#define DD 128

// Monotone order-preserving float->uint encoding.
__device__ __forceinline__ unsigned int enc_f(float f) {
    unsigned int u = __float_as_uint(f);
    return (u & 0x80000000u) ? ~u : (u | 0x80000000u);
}
__device__ __forceinline__ float dec_f(unsigned int u) {
    return __uint_as_float((u & 0x80000000u) ? (u ^ 0x80000000u) : ~u);
}
#define ENC_NEG_INF 0x007FFFFFu
#define ENC_POS_INF 0xFF800000u

// ---- non-temporal vector helpers ----
typedef float __attribute__((ext_vector_type(4))) f32x4;

__device__ __forceinline__ float4 nt_loadf4(const float* p) {
    f32x4 v = __builtin_nontemporal_load((const f32x4*)p);
    return make_float4(v.x, v.y, v.z, v.w);
}
__device__ __forceinline__ void nt_storef4(float* p, float4 v) {
    f32x4 t = {v.x, v.y, v.z, v.w};
    __builtin_nontemporal_store(t, (f32x4*)p);
}

// Wave-0 reduction of the 64 per-block minmax partials for batch b.
// part layout: [(b*64 + blk)*6 + k], k<3 = mn, k>=3 = mx. Result -> sm[6].
__device__ __forceinline__ void reduce_partials(const float* __restrict__ part,
                                                int b, float* sm, int tid) {
    if (tid < 64) {
        float v[6];
        #pragma unroll
        for (int k = 0; k < 6; k++) v[k] = part[(b * 64 + tid) * 6 + k];
        for (int o = 32; o > 0; o >>= 1) {
            #pragma unroll
            for (int k = 0; k < 3; k++) {
                v[k]     = fminf(v[k],     __shfl_xor(v[k],     o));
                v[k + 3] = fmaxf(v[k + 3], __shfl_xor(v[k + 3], o));
            }
        }
        if (tid == 0) {
            #pragma unroll
            for (int k = 0; k < 6; k++) sm[k] = v[k];
        }
    }
    __syncthreads();
}

// grid (64, BB), block 256. Pure minmax (cnt pipeline removed entirely).
__global__ void k_minmax(const float* __restrict__ xyz,
                         float* __restrict__ part, int N) {
    int b = blockIdx.y;
    int tid = threadIdx.x;
    int gid = blockIdx.x * blockDim.x + tid;
    int stride = gridDim.x * blockDim.x;

    float mn[3] = {INFINITY, INFINITY, INFINITY};
    float mx[3] = {-INFINITY, -INFINITY, -INFINITY};
    const float* base = xyz + (size_t)b * N * 3;
    const float4* p4 = (const float4*)base;
    int Ng = N >> 2;
    for (int g = gid; g < Ng; g += stride) {
        float4 a = p4[3 * g];
        float4 c = p4[3 * g + 1];
        float4 e = p4[3 * g + 2];
        // points: (a.x,a.y,a.z)(a.w,c.x,c.y)(c.z,c.w,e.x)(e.y,e.z,e.w)
        mn[0] = fminf(mn[0], fminf(fminf(a.x, a.w), fminf(c.z, e.y)));
        mx[0] = fmaxf(mx[0], fmaxf(fmaxf(a.x, a.w), fmaxf(c.z, e.y)));
        mn[1] = fminf(mn[1], fminf(fminf(a.y, c.x), fminf(c.w, e.z)));
        mx[1] = fmaxf(mx[1], fmaxf(fmaxf(a.y, c.x), fmaxf(c.w, e.z)));
        mn[2] = fminf(mn[2], fminf(fminf(a.z, c.y), fminf(e.x, e.w)));
        mx[2] = fmaxf(mx[2], fmaxf(fmaxf(a.z, c.y), fmaxf(e.x, e.w)));
    }
    for (int n = (Ng << 2) + gid; n < N; n += stride) {
        const float* p = base + (size_t)n * 3;
        #pragma unroll
        for (int k = 0; k < 3; k++) {
            float v = p[k];
            mn[k] = fminf(mn[k], v);
            mx[k] = fmaxf(mx[k], v);
        }
    }
    for (int o = 32; o > 0; o >>= 1) {
        #pragma unroll
        for (int k = 0; k < 3; k++) {
            mn[k] = fminf(mn[k], __shfl_xor(mn[k], o));
            mx[k] = fmaxf(mx[k], __shfl_xor(mx[k], o));
        }
    }
    __shared__ float smn[4][3], smx[4][3];
    int w = tid >> 6;
    if ((tid & 63) == 0) {
        #pragma unroll
        for (int k = 0; k < 3; k++) { smn[w][k] = mn[k]; smx[w][k] = mx[k]; }
    }
    __syncthreads();
    if (tid == 0) {
        float* pb = part + ((size_t)b * 64 + blockIdx.x) * 6;
        #pragma unroll
        for (int k = 0; k < 3; k++) {
            pb[k]     = fminf(fminf(smn[0][k], smn[1][k]), fminf(smn[2][k], smn[3][k]));
            pb[3 + k] = fmaxf(fmaxf(smx[0][k], smx[1][k]), fmaxf(smx[2][k], smx[3][k]));
        }
    }
}

__device__ __forceinline__ int quant_idx(float x, float y, float z,
                                         const float* mnv, const float* mxv) {
    const float CLIP_HI = 1.0f - 1e-6f;
    float p[3] = {x, y, z};
    int vi[3];
    #pragma unroll
    for (int k = 0; k < 3; k++) {
        float rng = (mxv[k] - mnv[k]) + 1e-8f;
        float t = (p[k] - mnv[k]) / rng;      // keep ref op order bit-exact
        t = fminf(fmaxf(t, 0.0f), CLIP_HI);
        int q = (int)floorf(t * 32.0f);
        q = min(max(q, 0), GG - 1);
        vi[k] = q;
    }
    return vi[0] * (GG * GG) + vi[1] * GG + vi[2];
}

// 4 points per thread: 3x float4 in, float4 out_idx + int4 idx_i out.
// No cnt atomics (counts are derived from idx_i inside k_fuse's tail blocks).
__global__ void k_idx(const float* __restrict__ xyz,
                      const float* __restrict__ part,
                      float* __restrict__ out_idx,
                      int* __restrict__ idx_i, int N) {
    int g = blockIdx.x * blockDim.x + threadIdx.x;   // group of 4 points
    int b = blockIdx.y;
    __shared__ float sm[6];
    reduce_partials(part, b, sm, threadIdx.x);
    float mnv[3] = {sm[0], sm[1], sm[2]};
    float mxv[3] = {sm[3], sm[4], sm[5]};

    int Ng = N >> 2;
    const float4* p4 = (const float4*)(xyz + (size_t)b * N * 3);
    if (g < Ng) {
        float4 a = p4[3 * g];
        float4 c = p4[3 * g + 1];
        float4 e = p4[3 * g + 2];
        int i0 = quant_idx(a.x, a.y, a.z, mnv, mxv);
        int i1 = quant_idx(a.w, c.x, c.y, mnv, mxv);
        int i2 = quant_idx(c.z, c.w, e.x, mnv, mxv);
        int i3 = quant_idx(e.y, e.z, e.w, mnv, mxv);
        size_t o = (size_t)b * N + 4 * (size_t)g;
        nt_storef4(out_idx + o, make_float4((float)i0, (float)i1,
                                            (float)i2, (float)i3));
        *(int4*)(idx_i + o) = make_int4(i0, i1, i2, i3);
    }
    if (g == 0) {   // serial tail (<=3 points)
        for (int n = Ng << 2; n < N; n++) {
            const float* p = xyz + ((size_t)b * N + n) * 3;
            int id = quant_idx(p[0], p[1], p[2], mnv, mxv);
            out_idx[(size_t)b * N + n] = (float)id;
            idx_i[(size_t)b * N + n] = id;
        }
    }
}

// Fused scatter-max: one block per (d, b); full voxel grid (128 KB) in LDS.
// blockIdx.x == 0 blocks (dispatched first, co-run with the 512 BW-bound
// compute blocks): LDS histogram of idx_i -> float counts, + minmax outputs.
// Compute blocks: NT feat loads / NT out stores (touch-once; keeps idx_i
// L2-resident) + read-before-atomic (benign race: LDS value monotone).
__global__ __launch_bounds__(1024) void k_fuse(const float* __restrict__ feat,
                                               const int* __restrict__ idx_i,
                                               float* __restrict__ out, int N,
                                               long off_cnt, long off_mm,
                                               const float* __restrict__ part) {
    int b = blockIdx.y;
    int t = threadIdx.x;                       // 0..1023
    const int T = 1024;
    __shared__ unsigned int s[NV];
    __shared__ float sm[6];

    if (blockIdx.x == 0) {
        // ---- per-voxel counts via LDS histogram ----
        uint4* s4 = (uint4*)s;
        uint4 z = make_uint4(0u, 0u, 0u, 0u);
        #pragma unroll
        for (int r = 0; r < NV / 4 / T; r++) s4[r * T + t] = z;
        __syncthreads();
        const int* ip = idx_i + (size_t)b * N;
        int n4 = N >> 2;
        const int4* i4 = (const int4*)ip;
        for (int i = t; i < n4; i += T) {
            int4 x = i4[i];
            atomicAdd(&s[x.x], 1u);
            atomicAdd(&s[x.y], 1u);
            atomicAdd(&s[x.z], 1u);
            atomicAdd(&s[x.w], 1u);
        }
        if (t == 0) {
            for (int n = n4 << 2; n < N; n++) atomicAdd(&s[ip[n]], 1u);
        }
        __syncthreads();
        float4* cf = (float4*)(out + off_cnt + (long)b * NV);
        #pragma unroll
        for (int r = 0; r < NV / 4 / T; r++) {
            int v = r * T + t;
            cf[v] = make_float4((float)s[4 * v], (float)s[4 * v + 1],
                                (float)s[4 * v + 2], (float)s[4 * v + 3]);
        }
        reduce_partials(part, b, sm, t);
        if (t < 3) {
            out[off_mm + b * 3 + t]      = sm[t];
            out[off_mm + 12 + b * 3 + t] = sm[3 + t];
        }
        return;
    }
    int d = blockIdx.x - 1;

    uint4* s4 = (uint4*)s;
    uint4 sent = make_uint4(ENC_NEG_INF, ENC_NEG_INF, ENC_NEG_INF, ENC_NEG_INF);
    #pragma unroll
    for (int v = 0; v < NV / 4 / T; v++) s4[v * T + t] = sent;
    __syncthreads();

    const float* fp = feat + ((size_t)b * DD + d) * N;
    const int*   ip = idx_i + (size_t)b * N;

    if ((N & 3) == 0) {
        const int4* i4 = (const int4*)ip;
        int n4 = N >> 2;
        for (int i = t; i < n4; i += T) {
            float4 f = nt_loadf4(fp + 4 * (size_t)i);
            int4   x = i4[i];
            unsigned int e0 = enc_f(f.x);
            unsigned int e1 = enc_f(f.y);
            unsigned int e2 = enc_f(f.z);
            unsigned int e3 = enc_f(f.w);
            if (e0 > s[x.x]) atomicMax(&s[x.x], e0);
            if (e1 > s[x.y]) atomicMax(&s[x.y], e1);
            if (e2 > s[x.z]) atomicMax(&s[x.z], e2);
            if (e3 > s[x.w]) atomicMax(&s[x.w], e3);
        }
    } else {
        for (int i = t; i < N; i += T) {
            unsigned int e = enc_f(fp[i]);
            if (e > s[ip[i]]) atomicMax(&s[ip[i]], e);
        }
    }
    __syncthreads();

    float* op = out + ((size_t)b * DD + d) * NV;
    #pragma unroll
    for (int r = 0; r < NV / 4 / T; r++) {
        int v = r * T + t;
        unsigned int u0 = s[4 * v + 0];
        unsigned int u1 = s[4 * v + 1];
        unsigned int u2 = s[4 * v + 2];
        unsigned int u3 = s[4 * v + 3];
        float4 o;
        o.x = (u0 == ENC_NEG_INF) ? 0.0f : dec_f(u0);
        o.y = (u1 == ENC_NEG_INF) ? 0.0f : dec_f(u1);
        o.z = (u2 == ENC_NEG_INF) ? 0.0f : dec_f(u2);
        o.w = (u3 == ENC_NEG_INF) ? 0.0f : dec_f(u3);
        nt_storef4(op + 4 * (size_t)v, o);
    }
}

// ---- legacy fallback (tiny ws): atomics directly into out [B,D,V] ----

__global__ void k_minmax_legacy(const float* __restrict__ xyz,
                                unsigned int* __restrict__ mm, int N) {
    int b = blockIdx.y;
    int tid = threadIdx.x;
    int gid = blockIdx.x * blockDim.x + tid;
    int stride = gridDim.x * blockDim.x;
    float mn[3] = {INFINITY, INFINITY, INFINITY};
    float mx[3] = {-INFINITY, -INFINITY, -INFINITY};
    const float* base = xyz + (size_t)b * N * 3;
    for (int n = gid; n < N; n += stride) {
        const float* p = base + (size_t)n * 3;
        #pragma unroll
        for (int k = 0; k < 3; k++) {
            float v = p[k];
            mn[k] = fminf(mn[k], v);
            mx[k] = fmaxf(mx[k], v);
        }
    }
    for (int o = 32; o > 0; o >>= 1) {
        #pragma unroll
        for (int k = 0; k < 3; k++) {
            mn[k] = fminf(mn[k], __shfl_xor(mn[k], o));
            mx[k] = fmaxf(mx[k], __shfl_xor(mx[k], o));
        }
    }
    __shared__ float smn[4][3], smx[4][3];
    int w = tid >> 6;
    if ((tid & 63) == 0) {
        #pragma unroll
        for (int k = 0; k < 3; k++) { smn[w][k] = mn[k]; smx[w][k] = mx[k]; }
    }
    __syncthreads();
    if (tid == 0) {
        #pragma unroll
        for (int k = 0; k < 3; k++) {
            float a = fminf(fminf(smn[0][k], smn[1][k]), fminf(smn[2][k], smn[3][k]));
            float c = fmaxf(fmaxf(smx[0][k], smx[1][k]), fmaxf(smx[2][k], smx[3][k]));
            atomicMin(&mm[b * 6 + k], enc_f(a));
            atomicMax(&mm[b * 6 + 3 + k], enc_f(c));
        }
    }
}

__global__ void k_idx_legacy(const float* __restrict__ xyz,
                             const unsigned int* __restrict__ mm,
                             float* __restrict__ out_idx,
                             int* __restrict__ cnt, int N) {
    int n = blockIdx.x * blockDim.x + threadIdx.x;
    int b = blockIdx.y;
    if (n >= N) return;
    float mnv[3], mxv[3];
    #pragma unroll
    for (int k = 0; k < 3; k++) {
        mnv[k] = dec_f(mm[b * 6 + k]);
        mxv[k] = dec_f(mm[b * 6 + 3 + k]);
    }
    const float* p = xyz + ((size_t)b * N + n) * 3;
    int idx = quant_idx(p[0], p[1], p[2], mnv, mxv);
    out_idx[(size_t)b * N + n] = (float)idx;
    atomicAdd(&cnt[b * NV + idx], 1);
}

__global__ void k_init_legacy(unsigned int* __restrict__ out_u, long nvox,
                              unsigned int* __restrict__ mm,
                              unsigned int* __restrict__ cnt, long ncnt) {
    long i = blockIdx.x * (long)blockDim.x + threadIdx.x;
    long stride = gridDim.x * (long)blockDim.x;
    for (long j = i; j < nvox; j += stride) out_u[j] = ENC_NEG_INF;
    for (long j = i; j < ncnt; j += stride) cnt[j] = 0u;
    if (i < BB * 6) mm[i] = ((i % 6) < 3) ? ENC_POS_INF : ENC_NEG_INF;
}

__global__ void k_scatter_legacy(const float* __restrict__ feat,
                                 const float* __restrict__ out_idx,
                                 unsigned int* __restrict__ vox, int N) {
    int n = blockIdx.x * blockDim.x + threadIdx.x;
    int b = blockIdx.y;
    if (n >= N) return;
    int idx = (int)out_idx[(size_t)b * N + n];
    const float* fp = feat + (size_t)b * DD * N + n;
    unsigned int* vp = vox + (size_t)b * DD * NV + idx;
    #pragma unroll 4
    for (int d = 0; d < DD; d++) {
        atomicMax(vp + (size_t)d * NV, enc_f(fp[(size_t)d * N]));
    }
}

__global__ void k_fin_vox_legacy(unsigned int* __restrict__ out_u,
                                 const int* __restrict__ cnt) {
    size_t i = blockIdx.x * (size_t)blockDim.x + threadIdx.x;
    int b = (int)(i >> 22);
    int v = (int)(i & (NV - 1));
    unsigned int u = out_u[i];
    float f = (cnt[b * NV + v] == 0) ? 0.0f : dec_f(u);
    ((float*)out_u)[i] = f;
}

__global__ void k_fin_tail_legacy(float* __restrict__ out,
                                  const unsigned int* __restrict__ mm,
                                  long off_cnt, long off_mm) {
    int i = blockIdx.x * blockDim.x + threadIdx.x;
    if (i < BB * NV) {
        int c = ((const int*)out)[off_cnt + i];
        out[off_cnt + i] = (float)c;
    }
    if (i < BB * 3) {
        int b = i / 3, k = i % 3;
        out[off_mm + i]      = dec_f(mm[b * 6 + k]);
        out[off_mm + 12 + i] = dec_f(mm[b * 6 + 3 + k]);
    }
}

extern "C" void kernel_launch(void* const* d_in, const int* in_sizes, int n_in,
                              void* d_out, int out_size, void* d_ws, size_t ws_size,
                              hipStream_t stream) {
    const float* features = (const float*)d_in[0];   // [B, D, N]
    const float* xyz      = (const float*)d_in[1];   // [B, N, 3]
    int N = in_sizes[1] / (BB * 3);                  // 100000

    float* out = (float*)d_out;
    unsigned int* ws_u = (unsigned int*)d_ws;

    const long nvox    = (long)BB * DD * NV;
    const long off_idx = nvox;
    const long off_cnt = off_idx + (long)BB * N;
    const long ncnt    = (long)BB * NV;
    const long off_mm  = off_cnt + ncnt;

    float* out_idx = out + off_idx;
    int*   cnt     = (int*)(out + off_cnt);

    int Ng = N >> 2;
    int nb4 = (Ng + 255) / 256; if (nb4 < 1) nb4 = 1;

    // fused path ws needs: idx_i [B*N] ints + part [B*64*6] floats
    bool fused = ws_size >= (size_t)((long)BB * N + (long)BB * 64 * 6) * 4
                 && (N & 3) == 0;

    if (fused) {
        int*   idx_i = (int*)ws_u;
        float* part  = (float*)(idx_i + (long)BB * N);

        k_minmax<<<dim3(64, BB), 256, 0, stream>>>(xyz, part, N);
        k_idx<<<dim3(nb4, BB), 256, 0, stream>>>(xyz, part, out_idx, idx_i, N);
        k_fuse<<<dim3(DD + 1, BB), 1024, 0, stream>>>(features, idx_i, out, N,
                                                      off_cnt, off_mm, part);
    } else {
        unsigned int* mm = ws_u;
        k_init_legacy<<<2048, 256, 0, stream>>>((unsigned int*)out, nvox, mm,
                                                (unsigned int*)cnt, ncnt);
        k_minmax_legacy<<<dim3(64, BB), 256, 0, stream>>>(xyz, mm, N);
        k_idx_legacy<<<dim3((N + 255) / 256, BB), 256, 0, stream>>>(
            xyz, mm, out_idx, cnt, N);
        k_scatter_legacy<<<dim3((N + 255) / 256, BB), 256, 0, stream>>>(
            features, out_idx, (unsigned int*)out, N);
        k_fin_vox_legacy<<<(unsigned)(nvox / 256), 256, 0, stream>>>(
            (unsigned int*)out, cnt);
        k_fin_tail_legacy<<<(int)((ncnt + 255) / 256), 256, 0, stream>>>(
            out, mm, off_cnt, off_mm);
    }
}